// Round 5
// baseline (332.956 us; speedup 1.0000x reference)
//
#include <hip/hip_runtime.h>
#include <hip/hip_fp16.h>

#define BATCH 4
#define NSEQ 2048
#define DMODEL 512
#define NHEAD 8
#define HDIM 64
#define LSEL 32
#define SROWU 2056    // u16 elements per score row (2048 + 8 pad)
#define MAXL 128

typedef __attribute__((ext_vector_type(8))) _Float16 f16x8;
typedef __attribute__((ext_vector_type(4))) float f32x4;

__device__ inline ushort f2h(float x) { __half h = __float2half(x); return *reinterpret_cast<ushort*>(&h); }
__device__ inline uint h2sort(ushort h) { return (h & 0x8000u) ? (uint)(h ^ 0xFFFFu) : (uint)(h | 0x8000u); }
__device__ inline float sort2f(uint su) {
    ushort hb = (su & 0x8000u) ? (ushort)(su ^ 0x8000u) : (ushort)(su ^ 0xFFFFu);
    __half th; *reinterpret_cast<ushort*>(&th) = hb;
    return __half2float(th);
}

// ---------------------------------------------------------------------------
// cvtW: W[512][512] fp32 -> Wt[n][k] fp16 (transposed), 4 matrices
// ---------------------------------------------------------------------------
__global__ __launch_bounds__(256) void cvtW_kernel(
    const float* __restrict__ Wq, const float* __restrict__ Wk,
    const float* __restrict__ Wv, const float* __restrict__ Wfc,
    ushort* __restrict__ Wt)
{
    const int z = blockIdx.y;
    const float* W = (z == 0) ? Wq : (z == 1) ? Wk : (z == 2) ? Wv : Wfc;
    ushort* O = Wt + (size_t)z * DMODEL * DMODEL;
    const int gt = blockIdx.x * 256 + threadIdx.x;
    const int n = gt & 511;
    const int kc = (gt >> 9) * 16;
    uint pk[8];
#pragma unroll
    for (int i = 0; i < 8; ++i) {
        uint lo = f2h(W[(size_t)(kc + 2 * i) * DMODEL + n]);
        uint hi = f2h(W[(size_t)(kc + 2 * i + 1) * DMODEL + n]);
        pk[i] = lo | (hi << 16);
    }
    uint4 u0 = {pk[0], pk[1], pk[2], pk[3]};
    uint4 u1 = {pk[4], pk[5], pk[6], pk[7]};
    *(uint4*)(O + (size_t)n * DMODEL + kc) = u0;
    *(uint4*)(O + (size_t)n * DMODEL + kc + 8) = u1;
}

// ---------------------------------------------------------------------------
// hgemm: OUT[8192,512] = A[8192,512] @ W (Wt stored [n][k] fp16).
// BM=64, BN=512, BK=32; 4 waves each 64x128; 16x16x32 f16 MFMA.
// MODE 0: A = fp32 (q/k/v), converted in-register; head-split fp16 out.
// MODE 1: A = fp16 (ao); fp32 row-major out.
// ---------------------------------------------------------------------------
template<int MODE>
__global__ __launch_bounds__(256, 2) void hgemm_kernel(
    const float* __restrict__ Fq, const float* __restrict__ Fk, const float* __restrict__ Fv,
    const ushort* __restrict__ A16,
    const ushort* __restrict__ Wt,
    ushort* __restrict__ O0, ushort* __restrict__ O1, ushort* __restrict__ O2,
    float* __restrict__ Ofc)
{
    __shared__ ushort Ah[64][40];
    __shared__ ushort Bh[512][40];   // also reused as epilogue staging

    const int tid = threadIdx.x;
    const int wave = tid >> 6, lane = tid & 63;
    const int lr = lane & 15, lg = lane >> 4;
    const int bm = blockIdx.x * 64;
    const int z = blockIdx.y;

    const float* Af = (MODE == 0) ? (z == 0 ? Fq : z == 1 ? Fk : Fv) : nullptr;
    const ushort* Wz = Wt + (size_t)((MODE == 0) ? z : 3) * (DMODEL * DMODEL);

    f32x4 acc[4][8];
#pragma unroll
    for (int i = 0; i < 4; ++i)
#pragma unroll
        for (int j = 0; j < 8; ++j) acc[i][j] = (f32x4){0.f, 0.f, 0.f, 0.f};

    const int sar = tid >> 2, sak = (tid & 3) * 8;

    for (int k0 = 0; k0 < DMODEL; k0 += 32) {
        __syncthreads();
        if (MODE == 0) {
            float4 fa = *(const float4*)(Af + (size_t)(bm + sar) * DMODEL + k0 + sak);
            float4 fb = *(const float4*)(Af + (size_t)(bm + sar) * DMODEL + k0 + sak + 4);
            uint4 pk;
            pk.x = (uint)f2h(fa.x) | ((uint)f2h(fa.y) << 16);
            pk.y = (uint)f2h(fa.z) | ((uint)f2h(fa.w) << 16);
            pk.z = (uint)f2h(fb.x) | ((uint)f2h(fb.y) << 16);
            pk.w = (uint)f2h(fb.z) | ((uint)f2h(fb.w) << 16);
            *(uint4*)&Ah[sar][sak] = pk;
        } else {
            *(uint4*)&Ah[sar][sak] = *(const uint4*)(A16 + (size_t)(bm + sar) * DMODEL + k0 + sak);
        }
#pragma unroll
        for (int i = 0; i < 8; ++i) {
            int n = sar + 64 * i;
            *(uint4*)&Bh[n][sak] = *(const uint4*)(Wz + (size_t)n * DMODEL + k0 + sak);
        }
        __syncthreads();
        f16x8 af[4];
#pragma unroll
        for (int fr = 0; fr < 4; ++fr) af[fr] = *(const f16x8*)&Ah[fr * 16 + lr][lg * 8];
#pragma unroll
        for (int fc2 = 0; fc2 < 8; ++fc2) {
            f16x8 bf = *(const f16x8*)&Bh[wave * 128 + fc2 * 16 + lr][lg * 8];
#pragma unroll
            for (int fr = 0; fr < 4; ++fr)
                acc[fr][fc2] = __builtin_amdgcn_mfma_f32_16x16x32_f16(af[fr], bf, acc[fr][fc2], 0, 0, 0);
        }
    }

    if (MODE == 1) {
#pragma unroll
        for (int fr = 0; fr < 4; ++fr)
#pragma unroll
            for (int fc2 = 0; fc2 < 8; ++fc2)
#pragma unroll
                for (int r = 0; r < 4; ++r)
                    Ofc[(size_t)(bm + fr * 16 + lg * 4 + r) * DMODEL + wave * 128 + fc2 * 16 + lr] = acc[fr][fc2][r];
        return;
    }

    // MODE 0 epilogue: LDS transpose -> coalesced head-split fp16 stores
    ushort* O = (z == 0) ? O0 : (z == 1) ? O1 : O2;
    const int b = bm >> 11;
    const int nseq0 = bm & (NSEQ - 1);
    ushort* smw = (ushort*)&Bh[0][0] + wave * (64 * 72);
#pragma unroll
    for (int hp = 0; hp < 2; ++hp) {
        __syncthreads();
#pragma unroll
        for (int f4 = 0; f4 < 4; ++f4) {
            int fc2 = hp * 4 + f4;
            int nl = f4 * 16 + lr;
#pragma unroll
            for (int fr = 0; fr < 4; ++fr)
#pragma unroll
                for (int r = 0; r < 4; ++r)
                    smw[(fr * 16 + lg * 4 + r) * 72 + nl] = f2h(acc[fr][fc2][r]);
        }
        __syncthreads();
        const int h = wave * 2 + hp;
        ushort* obase = O + ((size_t)(b * NHEAD + h) * NSEQ + nseq0) * HDIM;
#pragma unroll
        for (int i = 0; i < 8; ++i) {
            int m = i * 8 + (lane >> 3);
            int dc = (lane & 7) * 8;
            *(uint4*)(obase + (size_t)m * HDIM + dc) = *(const uint4*)(smw + m * 72 + dc);
        }
    }
}

// ---------------------------------------------------------------------------
// attention helpers
// ---------------------------------------------------------------------------
__device__ inline int wave_sum6(int c) {
    int tot = (int)__popcll(__ballot(c & 1));
    tot += (int)__popcll(__ballot(c & 2)) << 1;
    tot += (int)__popcll(__ballot(c & 4)) << 2;
    tot += (int)__popcll(__ballot(c & 8)) << 3;
    tot += (int)__popcll(__ballot(c & 16)) << 4;
    tot += (int)__popcll(__ballot(c & 32)) << 5;
    return tot;
}

__device__ uint full_thr(const ushort* Sr, int lane, uint lo0) {
    uint flo = lo0, fhi = 0xFFFFu;
#pragma unroll 1
    for (int it2 = 0; it2 < 16; ++it2) {
        uint mid = (flo + fhi + 1) >> 1, M = mid << 16;
        int cl = 0;
#pragma unroll
        for (int it = 0; it < 4; ++it) {
            uint4 r4 = *(const uint4*)(Sr + it * 512 + lane * 8);
            cl += ((r4.x << 16) >= M) + ((r4.x & 0xFFFF0000u) >= M);
            cl += ((r4.y << 16) >= M) + ((r4.y & 0xFFFF0000u) >= M);
            cl += ((r4.z << 16) >= M) + ((r4.z & 0xFFFF0000u) >= M);
            cl += ((r4.w << 16) >= M) + ((r4.w & 0xFFFF0000u) >= M);
        }
        bool ge = wave_sum6(cl) >= LSEL;
        flo = ge ? mid : flo;
        fhi = ge ? fhi : mid - 1;
    }
    return flo;
}

__device__ int recount(const ushort* Sr, int lane, uint th) {
    int cs = 0;
#pragma unroll
    for (int it = 0; it < 4; ++it) {
        uint4 r4 = *(const uint4*)(Sr + it * 512 + lane * 8);
        cs += ((r4.x << 16) >= th) + ((r4.x & 0xFFFF0000u) >= th);
        cs += ((r4.y << 16) >= th) + ((r4.y & 0xFFFF0000u) >= th);
        cs += ((r4.z << 16) >= th) + ((r4.z & 0xFFFF0000u) >= th);
        cs += ((r4.w << 16) >= th) + ((r4.w & 0xFFFF0000u) >= th);
    }
    return cs;
}

// slow-path extraction: full row scan, lane-major order
__device__ float extract_big(const ushort* Sr, int lane, uint th, float Mv,
                             int pre, ushort* li, float* lwp)
{
    const float L2E = 1.4426950408889634f;
    float wp = 0.f;
    int pos = pre;
#pragma unroll
    for (int it = 0; it < 4; ++it) {
        uint4 r4 = *(const uint4*)(Sr + it * 512 + lane * 8);
        uint ib = (uint)(it * 512 + lane * 8);
        uint wds[4] = {r4.x, r4.y, r4.z, r4.w};
#pragma unroll
        for (int c = 0; c < 4; ++c) {
            uint vL = wds[c] << 16, vH = wds[c] & 0xFFFF0000u;
            if (vL >= th) {
                float w = exp2f((sort2f(vL >> 16) - Mv) * L2E);
                if (pos < MAXL) { li[pos] = (ushort)(ib + c * 2); lwp[pos] = w; wp += w; }
                ++pos;
            }
            if (vH >= th) {
                float w = exp2f((sort2f(vH >> 16) - Mv) * L2E);
                if (pos < MAXL) { li[pos] = (ushort)(ib + c * 2 + 1); lwp[pos] = w; wp += w; }
                ++pos;
            }
        }
    }
#pragma unroll
    for (int off = 32; off >= 1; off >>= 1) wp += __shfl_xor(wp, off);
    return wp;
}

// fast-path extraction: selected values are the lane's sorted top-4 prefix
__device__ float extract_fast(uint t0, uint t1, uint t2, uint t3,
                              uint th, float Mv, int pre, ushort* li, float* lwp)
{
    const float L2E = 1.4426950408889634f;
    float wp = 0.f;
    uint tt[4] = {t0, t1, t2, t3};
#pragma unroll
    for (int i = 0; i < 4; ++i) {
        if (tt[i] >= th) {
            int pos = pre + i;
            float w = exp2f((sort2f(tt[i] >> 16) - Mv) * L2E);
            if (pos < MAXL) { li[pos] = (ushort)(tt[i] & 0xFFFFu); lwp[pos] = w; wp += w; }
        }
    }
#pragma unroll
    for (int off = 32; off >= 1; off >>= 1) wp += __shfl_xor(wp, off);
    return wp;
}

#define INS5(T0, T1, T2, T3, T4, P) { \
    uint m1_ = min(P, T0); T0 = max(P, T0); \
    uint m2_ = min(m1_, T1); T1 = max(m1_, T1); \
    uint m3_ = min(m2_, T2); T2 = max(m2_, T2); \
    uint m4_ = min(m3_, T3); T3 = max(m3_, T3); \
    T4 = max(m4_, T4); }

// ---------------------------------------------------------------------------
// attn v5: phase 1 = fp16 MFMA QK^T -> sortable u16 in LDS (as v4).
// phase 2: top-5 packed (val<<16|idx) prepass; ballot binary search on the
// 256-value top-4 sample; EXACTNESS TEST via 5th-largest (t4 >= thr -> rare
// slow path with full verify/search/extract); fast path extracts straight
// from registers (no second LDS pass). PV: wave split 32/32 over the two
// rows, half2 loads.
// ---------------------------------------------------------------------------
__global__ __launch_bounds__(512, 4) void attn_kernel(
    const ushort* __restrict__ qh, const ushort* __restrict__ kh,
    const ushort* __restrict__ vh, ushort* __restrict__ ao)
{
    __shared__ __align__(16) ushort Sbuf[16 * SROWU];
    __shared__ ushort lidx[16][MAXL];
    __shared__ float  lw[16][MAXL];

    const int tid = threadIdx.x;
    const int wave = tid >> 6;
    const int lane = tid & 63;
    const int bh = blockIdx.y;
    const int q0 = blockIdx.x * 16;
    const int lr = lane & 15;
    const int lg = lane >> 4;

    const ushort* Qb = qh + ((size_t)bh * NSEQ + q0) * HDIM;
    const ushort* Kb = kh + (size_t)bh * NSEQ * HDIM;

    f16x8 qf0 = *(const f16x8*)(Qb + lr * HDIM + lg * 8);
    f16x8 qf1 = *(const f16x8*)(Qb + lr * HDIM + 32 + lg * 8);

    // -------- Phase 1: scores --------
    for (int t = 0; t < 16; ++t) {
        const int k0 = wave * 256 + t * 16;
        const ushort* Kt = Kb + (size_t)k0 * HDIM;
        f16x8 a0 = *(const f16x8*)(Kt + lr * HDIM + lg * 8);
        f16x8 a1 = *(const f16x8*)(Kt + lr * HDIM + 32 + lg * 8);
        f32x4 acc = {0.f, 0.f, 0.f, 0.f};
        acc = __builtin_amdgcn_mfma_f32_16x16x32_f16(a0, qf0, acc, 0, 0, 0);
        acc = __builtin_amdgcn_mfma_f32_16x16x32_f16(a1, qf1, acc, 0, 0, 0);
        uint2 pk;
        pk.x = h2sort(f2h(acc[0] * 0.125f)) | (h2sort(f2h(acc[1] * 0.125f)) << 16);
        pk.y = h2sort(f2h(acc[2] * 0.125f)) | (h2sort(f2h(acc[3] * 0.125f)) << 16);
        *(uint2*)&Sbuf[lr * SROWU + k0 + lg * 4] = pk;
    }
    __syncthreads();

    // -------- Phase 2 --------
    const ushort* Vb = vh + (size_t)bh * NSEQ * HDIM;
    const int b = bh >> 3, hh = bh & 7;
    const unsigned long long below = (1ULL << lane) - 1ULL;

    const int qrA = wave * 2, qrB = qrA + 1;
    const ushort* SrA = &Sbuf[qrA * SROWU];
    const ushort* SrB = &Sbuf[qrB * SROWU];

    // top-5 packed prepass (both rows interleaved)
    uint a0 = 0, a1 = 0, a2 = 0, a3 = 0, a4 = 0;
    uint b0 = 0, b1 = 0, b2 = 0, b3 = 0, b4 = 0;
#pragma unroll
    for (int it = 0; it < 4; ++it) {
        uint4 ra = *(const uint4*)(SrA + it * 512 + lane * 8);
        uint4 rb = *(const uint4*)(SrB + it * 512 + lane * 8);
        uint ib = (uint)(it * 512 + lane * 8);
        uint p;
        p = (ra.x << 16) | (ib + 0); INS5(a0, a1, a2, a3, a4, p);
        p = (ra.x & 0xFFFF0000u) | (ib + 1); INS5(a0, a1, a2, a3, a4, p);
        p = (ra.y << 16) | (ib + 2); INS5(a0, a1, a2, a3, a4, p);
        p = (ra.y & 0xFFFF0000u) | (ib + 3); INS5(a0, a1, a2, a3, a4, p);
        p = (ra.z << 16) | (ib + 4); INS5(a0, a1, a2, a3, a4, p);
        p = (ra.z & 0xFFFF0000u) | (ib + 5); INS5(a0, a1, a2, a3, a4, p);
        p = (ra.w << 16) | (ib + 6); INS5(a0, a1, a2, a3, a4, p);
        p = (ra.w & 0xFFFF0000u) | (ib + 7); INS5(a0, a1, a2, a3, a4, p);
        p = (rb.x << 16) | (ib + 0); INS5(b0, b1, b2, b3, b4, p);
        p = (rb.x & 0xFFFF0000u) | (ib + 1); INS5(b0, b1, b2, b3, b4, p);
        p = (rb.y << 16) | (ib + 2); INS5(b0, b1, b2, b3, b4, p);
        p = (rb.y & 0xFFFF0000u) | (ib + 3); INS5(b0, b1, b2, b3, b4, p);
        p = (rb.z << 16) | (ib + 4); INS5(b0, b1, b2, b3, b4, p);
        p = (rb.z & 0xFFFF0000u) | (ib + 5); INS5(b0, b1, b2, b3, b4, p);
        p = (rb.w << 16) | (ib + 6); INS5(b0, b1, b2, b3, b4, p);
        p = (rb.w & 0xFFFF0000u) | (ib + 7); INS5(b0, b1, b2, b3, b4, p);
    }

    // wave max (exp shift)
    uint mxA = a0, mxB = b0;
#pragma unroll
    for (int off = 32; off >= 1; off >>= 1) {
        mxA = max(mxA, (uint)__shfl_xor((int)mxA, off));
        mxB = max(mxB, (uint)__shfl_xor((int)mxB, off));
    }
    const float MvA = sort2f(mxA >> 16), MvB = sort2f(mxB >> 16);

    // binary search: 32nd largest of the 256-value sample (rows interleaved)
    uint loA = 0, hiA = 0xFFFFu, loB = 0, hiB = 0xFFFFu;
#pragma unroll
    for (int it = 0; it < 16; ++it) {
        uint midA = (loA + hiA + 1) >> 1, MA = midA << 16;
        uint midB = (loB + hiB + 1) >> 1, MB = midB << 16;
        int cA = (a0 >= MA) + (a1 >= MA) + (a2 >= MA) + (a3 >= MA);
        int cB = (b0 >= MB) + (b1 >= MB) + (b2 >= MB) + (b3 >= MB);
        int totA = (int)__popcll(__ballot(cA & 1)) + ((int)__popcll(__ballot(cA & 2)) << 1)
                 + ((int)__popcll(__ballot(cA & 4)) << 2);
        int totB = (int)__popcll(__ballot(cB & 1)) + ((int)__popcll(__ballot(cB & 2)) << 1)
                 + ((int)__popcll(__ballot(cB & 4)) << 2);
        bool geA = totA >= LSEL, geB = totB >= LSEL;
        loA = geA ? midA : loA; hiA = geA ? hiA : midA - 1;
        loB = geB ? midB : loB; hiB = geB ? hiB : midB - 1;
    }

    uint thA = loA << 16, thB = loB << 16;

    // exactness test: sample is complete iff no lane's 5th-largest >= thr
    const bool missA = __any(a4 >= thA);
    const bool missB = __any(b4 >= thB);

    int cselA, cselB;
    if (!missA) {
        cselA = (a0 >= thA) + (a1 >= thA) + (a2 >= thA) + (a3 >= thA);
    } else {
        int cgt = recount(SrA, lane, thA + 0x10000u);     // count( > loA )
        if (wave_sum6(cgt) >= LSEL) { loA = full_thr(SrA, lane, loA); thA = loA << 16; }
        cselA = recount(SrA, lane, thA);
    }
    if (!missB) {
        cselB = (b0 >= thB) + (b1 >= thB) + (b2 >= thB) + (b3 >= thB);
    } else {
        int cgt = recount(SrB, lane, thB + 0x10000u);
        if (wave_sum6(cgt) >= LSEL) { loB = full_thr(SrB, lane, loB); thB = loB << 16; }
        cselB = recount(SrB, lane, thB);
    }

    // lane prefix + total of csel (6-bit ballots)
    int preA = 0, totA2 = 0, preB = 0, totB2 = 0;
#pragma unroll
    for (int bb = 0; bb < 6; ++bb) {
        unsigned long long mA = __ballot((cselA >> bb) & 1);
        unsigned long long mB = __ballot((cselB >> bb) & 1);
        preA += (int)__popcll(mA & below) << bb; totA2 += (int)__popcll(mA) << bb;
        preB += (int)__popcll(mB & below) << bb; totB2 += (int)__popcll(mB) << bb;
    }

    const float wsumA = missA
        ? extract_big(SrA, lane, thA, MvA, preA, &lidx[qrA][0], &lw[qrA][0])
        : extract_fast(a0, a1, a2, a3, thA, MvA, preA, &lidx[qrA][0], &lw[qrA][0]);
    const float wsumB = missB
        ? extract_big(SrB, lane, thB, MvB, preB, &lidx[qrB][0], &lw[qrB][0])
        : extract_fast(b0, b1, b2, b3, thB, MvB, preB, &lidx[qrB][0], &lw[qrB][0]);

    const int nkA = (totA2 < MAXL) ? totA2 : MAXL;
    const int nkB = (totB2 < MAXL) ? totB2 : MAXL;

    // -------- sparse PV: wave split 32/32 over rows A/B, half2 loads --------
    const int half = lane >> 5;            // 0 -> row A, 1 -> row B
    const int dp = lane & 31;              // dim pair
    const int qrMy = qrA + half;
    const int nkMy = half ? nkB : nkA;
    const float wsMy = half ? wsumB : wsumA;
    const __half2* V2 = reinterpret_cast<const __half2*>(Vb);

    float ox = 0.f, oy = 0.f;
    int j = 0;
    for (; j + 4 <= nkMy; j += 4) {
        int i0 = lidx[qrMy][j + 0]; float w0 = lw[qrMy][j + 0];
        int i1 = lidx[qrMy][j + 1]; float w1 = lw[qrMy][j + 1];
        int i2 = lidx[qrMy][j + 2]; float w2 = lw[qrMy][j + 2];
        int i3 = lidx[qrMy][j + 3]; float w3 = lw[qrMy][j + 3];
        float2 v0 = __half22float2(V2[(size_t)i0 * 32 + dp]);
        float2 v1 = __half22float2(V2[(size_t)i1 * 32 + dp]);
        float2 v2 = __half22float2(V2[(size_t)i2 * 32 + dp]);
        float2 v3 = __half22float2(V2[(size_t)i3 * 32 + dp]);
        ox += w0 * v0.x + w1 * v1.x + w2 * v2.x + w3 * v3.x;
        oy += w0 * v0.y + w1 * v1.y + w2 * v2.y + w3 * v3.y;
    }
    for (; j < nkMy; ++j) {
        int i0 = lidx[qrMy][j]; float w0 = lw[qrMy][j];
        float2 v0 = __half22float2(V2[(size_t)i0 * 32 + dp]);
        ox += w0 * v0.x; oy += w0 * v0.y;
    }

    const float inv = 1.f / wsMy;
    uint opk = (uint)f2h(ox * inv) | ((uint)f2h(oy * inv) << 16);
    *(uint*)(ao + ((size_t)(b * NSEQ) + q0 + qrMy) * DMODEL + hh * HDIM + dp * 2) = opk;
}

// ---------------------------------------------------------------------------
// LN: out = LN(fc_raw + resid) * g + b ; 4 waves/block, 1 row/wave
// ---------------------------------------------------------------------------
__global__ __launch_bounds__(256) void ln_kernel(
    const float* __restrict__ fcr, const float* __restrict__ resid,
    const float* __restrict__ g, const float* __restrict__ bta, float* __restrict__ out)
{
    const int row = blockIdx.x * 4 + (threadIdx.x >> 6);
    const int lane = threadIdx.x & 63;
    const size_t base = (size_t)row * DMODEL + lane * 8;
    float4 xa = *(const float4*)(fcr + base);
    float4 xb = *(const float4*)(fcr + base + 4);
    float4 ra = *(const float4*)(resid + base);
    float4 rb = *(const float4*)(resid + base + 4);
    xa.x += ra.x; xa.y += ra.y; xa.z += ra.z; xa.w += ra.w;
    xb.x += rb.x; xb.y += rb.y; xb.z += rb.z; xb.w += rb.w;
    float sum = xa.x + xa.y + xa.z + xa.w + xb.x + xb.y + xb.z + xb.w;
    float sq = xa.x * xa.x + xa.y * xa.y + xa.z * xa.z + xa.w * xa.w
             + xb.x * xb.x + xb.y * xb.y + xb.z * xb.z + xb.w * xb.w;
#pragma unroll
    for (int off = 32; off >= 1; off >>= 1) {
        sum += __shfl_xor(sum, off);
        sq += __shfl_xor(sq, off);
    }
    float mean = sum * (1.f / 512.f);
    float var = sq * (1.f / 512.f) - mean * mean;
    float rstd = rsqrtf(var + 1e-6f);
    float4 ga = *(const float4*)(g + lane * 8);
    float4 gb = *(const float4*)(g + lane * 8 + 4);
    float4 ba = *(const float4*)(bta + lane * 8);
    float4 bb = *(const float4*)(bta + lane * 8 + 4);
    float4 oa, ob;
    oa.x = (xa.x - mean) * rstd * ga.x + ba.x;
    oa.y = (xa.y - mean) * rstd * ga.y + ba.y;
    oa.z = (xa.z - mean) * rstd * ga.z + ba.z;
    oa.w = (xa.w - mean) * rstd * ga.w + ba.w;
    ob.x = (xb.x - mean) * rstd * gb.x + bb.x;
    ob.y = (xb.y - mean) * rstd * gb.y + bb.y;
    ob.z = (xb.z - mean) * rstd * gb.z + bb.z;
    ob.w = (xb.w - mean) * rstd * gb.w + bb.w;
    *(float4*)(out + base) = oa;
    *(float4*)(out + base + 4) = ob;
}

extern "C" void kernel_launch(void* const* d_in, const int* in_sizes, int n_in,
                              void* d_out, int out_size, void* d_ws, size_t ws_size,
                              hipStream_t stream)
{
    (void)in_sizes; (void)n_in; (void)out_size; (void)ws_size;

    const float* q   = (const float*)d_in[0];
    const float* k   = (const float*)d_in[1];
    const float* v   = (const float*)d_in[2];
    const float* Wq  = (const float*)d_in[3];
    const float* Wk  = (const float*)d_in[4];
    const float* Wv  = (const float*)d_in[5];
    const float* Wfc = (const float*)d_in[6];
    const float* g   = (const float*)d_in[7];
    const float* b   = (const float*)d_in[8];
    float* out = (float*)d_out;

    const size_t SZ = (size_t)BATCH * NSEQ * DMODEL;      // 4,194,304
    const size_t WSZ = (size_t)DMODEL * DMODEL;           // 262,144
    ushort* Wt = (ushort*)d_ws;                           // 4 matrices, 2 MB
    ushort* qh = Wt + 4 * WSZ;
    ushort* kh = qh + SZ;
    ushort* vh = kh + SZ;
    ushort* ao = vh + SZ;
    float* fc_raw = (float*)qh;   // overlays qh+kh (dead after attn)

    cvtW_kernel<<<dim3(64, 4), 256, 0, stream>>>(Wq, Wk, Wv, Wfc, Wt);
    hgemm_kernel<0><<<dim3(128, 3), 256, 0, stream>>>(q, k, v, nullptr, Wt, qh, kh, vh, nullptr);
    attn_kernel<<<dim3(NSEQ / 16, BATCH * NHEAD), 512, 0, stream>>>(qh, kh, vh, ao);
    hgemm_kernel<1><<<dim3(128, 1), 256, 0, stream>>>(nullptr, nullptr, nullptr, ao, Wt, nullptr, nullptr, nullptr, fc_raw);
    ln_kernel<<<(BATCH * NSEQ) / 4, 256, 0, stream>>>(fc_raw, q, g, b, out);
}